// Round 3
// baseline (217.501 us; speedup 1.0000x reference)
//
#include <hip/hip_runtime.h>

#define IN_FEAT 128
#define OUT_FEAT 64
#define LRELU_ALPHA 0.2f
#define BUK_SHIFT 7        // coarse bucket = src >> 7 (128 nodes/bucket)
#define BUK_SIZE 128
#define MAX_NBUK 1024      // N <= 131072
#define D_BITS 17          // dst < 2^17 (N <= 131072): pk = (sl<<17)|dst
#define D_MASK 0x1FFFF
#define BIN_PER_THREAD 32  // 8192 edges per bin block (8->32 reverted: 8 cost +18us
                           // in per-block fixed overhead + write fragmentation)
#define CAP 2560           // LDS record capacity per chunk (mean bucket ~2046)
#define STAGE_MAX 5        // CAP / 512
#define HIST_BLOCKS 512

typedef __attribute__((ext_vector_type(8))) short bf16x8;
typedef __attribute__((ext_vector_type(4))) float floatx4;

// fp32 -> bf16 bits, round-to-nearest-even (inputs are finite; no NaN guard)
__device__ __forceinline__ short f2bf(float f) {
  union { float f; unsigned u; } v; v.f = f;
  unsigned r = v.u + 0x7fff + ((v.u >> 16) & 1);
  return (short)(r >> 16);
}
__device__ __forceinline__ float bf2f(unsigned short s) {
  union { unsigned u; float f; } v; v.u = ((unsigned)s) << 16;
  return v.f;
}

// ---------------------------------------------------------------------------
// Kernel 1 (merged): blocks [0, grid_gemm) do h = bf16(x) @ bf16(W) via MFMA
// 16x16x32 (+ fused s1 = h@a1, s2 = h@a2); blocks [grid_gemm, +HIST_BLOCKS)
// do the coarse src-bucket histogram. Disjoint inputs -> hist traffic hides
// under gemm compute, one launch saved.
// ---------------------------------------------------------------------------
__global__ __launch_bounds__(256) void gemm_hist_kernel(
    const float* __restrict__ x, const float* __restrict__ W,
    const float* __restrict__ a, unsigned short* __restrict__ h,
    float* __restrict__ s1, float* __restrict__ s2, int N,
    const int* __restrict__ src, int* __restrict__ cbuk, int E,
    int grid_gemm) {
  __shared__ __align__(16) short Wt[64 * 136];  // W^T bf16, stride 136
  __shared__ float a_sh[2 * OUT_FEAT];
  __shared__ int lh[MAX_NBUK];

  if (blockIdx.x >= grid_gemm) {
    // ---- coarse histogram part (uniform branch per block) ----
    int t = threadIdx.x;
    for (int i = t; i < MAX_NBUK; i += 256) lh[i] = 0;
    __syncthreads();
    int hb = blockIdx.x - grid_gemm;
    for (int e = hb * 256 + t; e < E; e += HIST_BLOCKS * 256)
      atomicAdd(&lh[src[e] >> BUK_SHIFT], 1);
    __syncthreads();
    for (int i = t; i < MAX_NBUK; i += 256)
      if (lh[i] > 0) atomicAdd(&cbuk[i], lh[i]);
    return;
  }

  // ---- gemm part ----
  if (threadIdx.x < 2 * OUT_FEAT) a_sh[threadIdx.x] = a[threadIdx.x];
  for (int i = threadIdx.x; i < IN_FEAT * OUT_FEAT; i += 256) {
    int k = i >> 6, n = i & 63;
    Wt[n * 136 + k] = f2bf(W[i]);
  }
  __syncthreads();

  int wave = threadIdx.x >> 6;
  int lane = threadIdx.x & 63;
  int l = lane & 15;
  int quad = lane >> 4;

  int row_base = blockIdx.x * 64 + wave * 16;
  int m = row_base + l;
  int m_c = m < N ? m : N - 1;

  bf16x8 bfrag[4][4];
#pragma unroll
  for (int kt = 0; kt < 4; ++kt)
#pragma unroll
    for (int nt = 0; nt < 4; ++nt)
      bfrag[kt][nt] = *(const bf16x8*)&Wt[(nt * 16 + l) * 136 + kt * 32 + quad * 8];

  floatx4 acc[4] = {floatx4{0,0,0,0}, floatx4{0,0,0,0}, floatx4{0,0,0,0}, floatx4{0,0,0,0}};
  const float* xrow = x + (size_t)m_c * IN_FEAT;
#pragma unroll
  for (int kt = 0; kt < 4; ++kt) {
    float4 xa = *(const float4*)(xrow + kt * 32 + quad * 8);
    float4 xb = *(const float4*)(xrow + kt * 32 + quad * 8 + 4);
    bf16x8 af;
    af[0] = f2bf(xa.x); af[1] = f2bf(xa.y); af[2] = f2bf(xa.z); af[3] = f2bf(xa.w);
    af[4] = f2bf(xb.x); af[5] = f2bf(xb.y); af[6] = f2bf(xb.z); af[7] = f2bf(xb.w);
#pragma unroll
    for (int nt = 0; nt < 4; ++nt)
      acc[nt] = __builtin_amdgcn_mfma_f32_16x16x32_bf16(af, bfrag[kt][nt], acc[nt], 0, 0, 0);
  }

  int out_row = row_base + quad * 4;
#pragma unroll
  for (int reg = 0; reg < 4; ++reg) {
    int r = out_row + reg;
    if (r < N) {
#pragma unroll
      for (int nt = 0; nt < 4; ++nt)
        h[(size_t)r * OUT_FEAT + nt * 16 + l] = (unsigned short)f2bf(acc[nt][reg]);
    }
  }

  float p1[4] = {0, 0, 0, 0}, p2[4] = {0, 0, 0, 0};
#pragma unroll
  for (int nt = 0; nt < 4; ++nt) {
    float a1v = a_sh[nt * 16 + l];
    float a2v = a_sh[OUT_FEAT + nt * 16 + l];
#pragma unroll
    for (int reg = 0; reg < 4; ++reg) {
      p1[reg] += acc[nt][reg] * a1v;
      p2[reg] += acc[nt][reg] * a2v;
    }
  }
#pragma unroll
  for (int off = 1; off < 16; off <<= 1) {
#pragma unroll
    for (int reg = 0; reg < 4; ++reg) {
      p1[reg] += __shfl_xor(p1[reg], off);
      p2[reg] += __shfl_xor(p2[reg], off);
    }
  }
  if (l < 4) {
    int r = out_row + l;
    if (r < N) {
      float v1 = l == 0 ? p1[0] : (l == 1 ? p1[1] : (l == 2 ? p1[2] : p1[3]));
      float v2 = l == 0 ? p2[0] : (l == 1 ? p2[1] : (l == 2 ? p2[2] : p2[3]));
      s1[r] = v1;
      s2[r] = v2;
    }
  }
}

// ---------------------------------------------------------------------------
// Parallel exclusive scan of bucket counts -> buk_off (NB+1) + bin cursors.
// Two-level __shfl_up scan (16 waves of 64, then 16-element wave-sum scan).
// ---------------------------------------------------------------------------
__global__ __launch_bounds__(1024) void scan_buckets_kernel(
    const int* __restrict__ cbuk, int* __restrict__ buk_off,
    int* __restrict__ buk_cursor, int NB) {
  __shared__ int wsum[16];
  __shared__ int wexcl[16];
  int t = threadIdx.x;
  int lane = t & 63;
  int w = t >> 6;

  int v = (t < NB) ? cbuk[t] : 0;
  int x = v;
#pragma unroll
  for (int off = 1; off < 64; off <<= 1) {
    int y = __shfl_up(x, off);
    if (lane >= off) x += y;
  }
  if (lane == 63) wsum[w] = x;
  __syncthreads();
  if (t < 64) {
    int s = (t < 16) ? wsum[t] : 0;
    int xs = s;
#pragma unroll
    for (int off = 1; off < 16; off <<= 1) {
      int y = __shfl_up(xs, off);
      if (lane >= off) xs += y;
    }
    if (t < 16) wexcl[t] = xs - s;
  }
  __syncthreads();
  int excl = wexcl[w] + x - v;   // exclusive prefix over cbuk[0..t)
  if (t < NB) {
    buk_off[t] = excl;
    buk_cursor[t] = excl;
  }
  if (t == NB) buk_off[NB] = excl;                        // NB < 1024
  if (NB == 1024 && t == 1023) buk_off[NB] = excl + v;    // safety for max N
}

// ---------------------------------------------------------------------------
// Bin by src>>7. Pure routing: bukdata[pos] = (sl<<17)|dst, 4B/edge (6.4MB).
// Per-block LDS histogram + one global atomic per (block,bucket) ->
// contiguous ~42B write runs per bucket (L2-merged). 196 blocks of 32
// edges/thread measured faster than 782x8 (round 2: +18us regression).
// ---------------------------------------------------------------------------
__global__ __launch_bounds__(256) void bin_kernel(
    const int* __restrict__ src, const int* __restrict__ dst,
    int* __restrict__ buk_cursor, int* __restrict__ bukdata, int E) {
  __shared__ int lhist[MAX_NBUK];
  __shared__ int lbase[MAX_NBUK];
  int t = threadIdx.x;
  for (int i = t; i < MAX_NBUK; i += 256) lhist[i] = 0;
  __syncthreads();

  int base_e = blockIdx.x * (256 * BIN_PER_THREAD);
  int s[BIN_PER_THREAD], d[BIN_PER_THREAD];
#pragma unroll
  for (int j = 0; j < BIN_PER_THREAD; ++j) {
    int e = base_e + j * 256 + t;
    bool valid = e < E;
    s[j] = valid ? src[e] : 0;
    d[j] = valid ? dst[e] : 0;
    if (valid) atomicAdd(&lhist[s[j] >> BUK_SHIFT], 1);
  }
  __syncthreads();
  for (int i = t; i < MAX_NBUK; i += 256) {
    int c = lhist[i];
    lbase[i] = c > 0 ? atomicAdd(&buk_cursor[i], c) : 0;
    lhist[i] = 0;  // reuse as in-block cursor
  }
  __syncthreads();
#pragma unroll
  for (int j = 0; j < BIN_PER_THREAD; ++j) {
    int e = base_e + j * 256 + t;
    if (e < E) {
      int b = s[j] >> BUK_SHIFT;
      int pos = lbase[b] + atomicAdd(&lhist[b], 1);
      bukdata[pos] = ((s[j] & (BUK_SIZE - 1)) << D_BITS) | d[j];
    }
  }
}

// ---------------------------------------------------------------------------
// Fused sort+aggregate: one 512-thread block (8 waves) per 128-node bucket
// (~2048 edges). Per chunk: stage packed edges in regs, LDS histogram, block
// scan, scatter {dst,ee} into LDS sorted by node. Aggregation walks FOUR
// nodes per wave concurrently (independent accumulators, interleaved loads):
// 16 gather instructions (32 edges) in flight per k-iteration. This phase is
// request-concurrency-bound (HBM 5-20%, VALU 44%, occ 27%: nothing
// saturated; h thrashes the 4MB per-XCD L2 so gathers see ~L3 latency);
// 2-node interleave gave -13%, extending the same lever. Predicated-off
// slots clamp to the node's first record -> same 128B line each iteration
// -> L1-hot, doesn't consume fabric concurrency.
// ---------------------------------------------------------------------------
__global__ __launch_bounds__(512) void bucket_sort_aggregate_kernel(
    const int* __restrict__ bukdata, const int* __restrict__ buk_off,
    const float* __restrict__ s1, const float* __restrict__ s2,
    const unsigned short* __restrict__ h, float* __restrict__ out, int N) {
  __shared__ float s1sh[BUK_SIZE];
  __shared__ int lhist[BUK_SIZE];
  __shared__ int loffs[BUK_SIZE];
  __shared__ int lcur[BUK_SIZE];
  __shared__ int wtot[2];
  __shared__ int2 lrec[CAP];  // 20KB

  int t = threadIdx.x;
  int buk = blockIdx.x;
  int beg = buk_off[buk];
  int end = buk_off[buk + 1];
  int node_base = buk << BUK_SHIFT;

  if (t < BUK_SIZE) {
    int ng = node_base + t;
    s1sh[t] = ng < N ? s1[ng] : 0.f;
  }

  int wid = t >> 6;      // wave 0..7; owns nodes wid, wid+8, ..., wid+120
  int lane = t & 63;
  int half = lane >> 5;
  int c2 = lane & 31;

  float ax[16], ay[16], rs[16];
#pragma unroll
  for (int j = 0; j < 16; ++j) { ax[j] = 0.f; ay[j] = 0.f; rs[j] = 0.f; }

  for (int cbeg = beg; cbeg < end; cbeg += CAP) {
    int cnt = min(end - cbeg, CAP);

    if (t < BUK_SIZE) lhist[t] = 0;
    __syncthreads();  // also covers s1sh on first chunk

    // ---- Stage: load packed edges, compute ee once/edge, LDS histogram ----
    int dreg[STAGE_MAX];
    int slreg[STAGE_MAX];
    float ereg[STAGE_MAX];
#pragma unroll
    for (int j = 0; j < STAGE_MAX; ++j) {
      int i = t + j * 512;
      bool v = i < cnt;
      int pk = v ? bukdata[cbeg + i] : 0;
      slreg[j] = pk >> D_BITS;
      dreg[j] = pk & D_MASK;
      float sc = s1sh[slreg[j]] + (v ? s2[dreg[j]] : 0.f);
      ereg[j] = __expf(-(sc > 0.f ? sc : LRELU_ALPHA * sc));
      if (v) atomicAdd(&lhist[slreg[j]], 1);
    }
    __syncthreads();

    // ---- Block scan over 128 counters (threads 0..127, 2 waves) ----
    int hv = (t < BUK_SIZE) ? lhist[t] : 0;
    int xs = hv;
#pragma unroll
    for (int off = 1; off < 64; off <<= 1) {
      int y = __shfl_up(xs, off);
      if (lane >= off) xs += y;
    }
    if (t < BUK_SIZE && lane == 63) wtot[t >> 6] = xs;
    __syncthreads();
    if (t < BUK_SIZE) {
      int base = (t >> 6) ? wtot[0] : 0;
      int excl = base + xs - hv;
      loffs[t] = excl;
      lcur[t] = excl;
    }
    __syncthreads();

    // ---- Scatter into LDS, sorted by node ----
#pragma unroll
    for (int j = 0; j < STAGE_MAX; ++j) {
      int i = t + j * 512;
      if (i < cnt) {
        int pos = atomicAdd(&lcur[slreg[j]], 1);
        lrec[pos] = make_int2(dreg[j], __float_as_int(ereg[j]));
      }
    }
    __syncthreads();

    // ---- Aggregate: 4 nodes per wave in flight (independent chains) ----
#pragma unroll
    for (int p = 0; p < 4; ++p) {
      int nl0 = wid + (4 * p + 0) * 8;
      int nl1 = wid + (4 * p + 1) * 8;
      int nl2 = wid + (4 * p + 2) * 8;
      int nl3 = wid + (4 * p + 3) * 8;
      int c0 = lhist[nl0], c1 = lhist[nl1], c2c = lhist[nl2], c3 = lhist[nl3];
      int o0 = c0 > 0 ? loffs[nl0] : 0;  // clamp: lrec[0] valid (cnt>=1)
      int o1 = c1 > 0 ? loffs[nl1] : 0;
      int o2 = c2c > 0 ? loffs[nl2] : 0;
      int o3 = c3 > 0 ? loffs[nl3] : 0;
      int kmax = max(max(c0, c1), max(c2c, c3));
      for (int k = 0; k < kmax; k += 8) {   // trip count wave-uniform
#pragma unroll
        for (int j = 0; j < 4; ++j) {
          int idx = k + 2 * j + half;
          bool v0 = idx < c0, v1 = idx < c1, v2 = idx < c2c, v3 = idx < c3;
          int2 r0 = lrec[o0 + (v0 ? idx : 0)];
          int2 r1 = lrec[o1 + (v1 ? idx : 0)];
          int2 r2 = lrec[o2 + (v2 ? idx : 0)];
          int2 r3 = lrec[o3 + (v3 ? idx : 0)];
          float e0 = v0 ? __int_as_float(r0.y) : 0.f;
          float e1 = v1 ? __int_as_float(r1.y) : 0.f;
          float e2 = v2 ? __int_as_float(r2.y) : 0.f;
          float e3 = v3 ? __int_as_float(r3.y) : 0.f;
          unsigned h0 = *(const unsigned*)&h[r0.x * OUT_FEAT + 2 * c2];
          unsigned h1 = *(const unsigned*)&h[r1.x * OUT_FEAT + 2 * c2];
          unsigned h2 = *(const unsigned*)&h[r2.x * OUT_FEAT + 2 * c2];
          unsigned h3 = *(const unsigned*)&h[r3.x * OUT_FEAT + 2 * c2];
          rs[4 * p + 0] += e0; ax[4 * p + 0] += e0 * bf2f(h0 & 0xffff); ay[4 * p + 0] += e0 * bf2f(h0 >> 16);
          rs[4 * p + 1] += e1; ax[4 * p + 1] += e1 * bf2f(h1 & 0xffff); ay[4 * p + 1] += e1 * bf2f(h1 >> 16);
          rs[4 * p + 2] += e2; ax[4 * p + 2] += e2 * bf2f(h2 & 0xffff); ay[4 * p + 2] += e2 * bf2f(h2 >> 16);
          rs[4 * p + 3] += e3; ax[4 * p + 3] += e3 * bf2f(h3 & 0xffff); ay[4 * p + 3] += e3 * bf2f(h3 >> 16);
        }
      }
    }
    __syncthreads();  // protect lhist/loffs/lrec before next chunk
  }

  // ---- Finalize: cross-half reduce, out = elu(acc / rowsum) ----
#pragma unroll
  for (int nn = 0; nn < 16; ++nn) {
    float r = rs[nn] + __shfl_xor(rs[nn], 32);
    float xv = ax[nn] + __shfl_xor(ax[nn], 32);
    float yv = ay[nn] + __shfl_xor(ay[nn], 32);
    int ng = node_base + wid + nn * 8;
    if (ng < N && half == 0) {
      float vx = xv / r, vy = yv / r;
      vx = vx > 0.f ? vx : __expf(vx) - 1.f;
      vy = vy > 0.f ? vy : __expf(vy) - 1.f;
      *(float2*)&out[(size_t)ng * OUT_FEAT + 2 * c2] = make_float2(vx, vy);
    }
  }
}

extern "C" void kernel_launch(void* const* d_in, const int* in_sizes, int n_in,
                              void* d_out, int out_size, void* d_ws, size_t ws_size,
                              hipStream_t stream) {
  const float* x = (const float*)d_in[0];  // (N, 128) fp32
  const float* W = (const float*)d_in[1];  // (128, 64) fp32
  const float* a = (const float*)d_in[2];  // (1, 128) fp32
  const int* edge = (const int*)d_in[3];   // (2, E) int32

  const int N = in_sizes[0] / IN_FEAT;
  const int E = in_sizes[3] / 2;
  const int* src = edge;
  const int* dst = edge + E;

  float* out = (float*)d_out;  // (N, 64) fp32

  // Workspace layout (~21 MB)
  char* p = (char*)d_ws;
  unsigned short* h = (unsigned short*)p; p += (size_t)N * OUT_FEAT * sizeof(unsigned short);
  float* s1 = (float*)p;      p += (size_t)N * sizeof(float);
  float* s2 = (float*)p;      p += (size_t)N * sizeof(float);
  int* cbuk = (int*)p;        p += MAX_NBUK * sizeof(int);
  int* buk_off = (int*)p;     p += (MAX_NBUK + 1) * sizeof(int);
  int* buk_cursor = (int*)p;  p += MAX_NBUK * sizeof(int);
  int* bukdata = (int*)p;     p += (size_t)E * sizeof(int);

  const int NB = (N + BUK_SIZE - 1) / BUK_SIZE;  // 782 buckets

  hipMemsetAsync(cbuk, 0, MAX_NBUK * sizeof(int), stream);

  int grid_gemm = (N + 63) / 64;
  gemm_hist_kernel<<<grid_gemm + HIST_BLOCKS, 256, 0, stream>>>(
      x, W, a, h, s1, s2, N, src, cbuk, E, grid_gemm);

  scan_buckets_kernel<<<1, 1024, 0, stream>>>(cbuk, buk_off, buk_cursor, NB);

  int grid_bin = (E + 256 * BIN_PER_THREAD - 1) / (256 * BIN_PER_THREAD);
  bin_kernel<<<grid_bin, 256, 0, stream>>>(src, dst, buk_cursor, bukdata, E);

  bucket_sort_aggregate_kernel<<<NB, 512, 0, stream>>>(bukdata, buk_off, s1, s2, h, out, N);
}

// Round 4
// 194.381 us; speedup vs baseline: 1.1189x; 1.1189x over previous
//
#include <hip/hip_runtime.h>

#define IN_FEAT 128
#define OUT_FEAT 64
#define LRELU_ALPHA 0.2f
#define BUK_SHIFT 7        // coarse bucket = src >> 7 (128 nodes/bucket)
#define BUK_SIZE 128
#define MAX_NBUK 1024      // N <= 131072
#define D_BITS 17          // dst < 2^17 (N <= 131072): pk = (sl<<17)|dst
#define D_MASK 0x1FFFF
#define BIN_THREADS 512
#define BIN_PER_THREAD 16  // 8192 edges per bin block; 196 blocks (proven best
                           // block count; 782 blocks cost +18us in cursor-atomic
                           // contention). 512 thr = 2x waves to hide scatter latency.
#define CAP 2560           // LDS record capacity per chunk (mean bucket ~2046)
#define STAGE_MAX 5        // CAP / 512
#define HIST_BLOCKS 512

typedef __attribute__((ext_vector_type(8))) short bf16x8;
typedef __attribute__((ext_vector_type(4))) float floatx4;

// fp32 -> bf16 bits, round-to-nearest-even (inputs are finite; no NaN guard)
__device__ __forceinline__ short f2bf(float f) {
  union { float f; unsigned u; } v; v.f = f;
  unsigned r = v.u + 0x7fff + ((v.u >> 16) & 1);
  return (short)(r >> 16);
}
__device__ __forceinline__ float bf2f(unsigned short s) {
  union { unsigned u; float f; } v; v.u = ((unsigned)s) << 16;
  return v.f;
}

// ---------------------------------------------------------------------------
// Kernel 1 (merged): blocks [0, grid_gemm) do h = bf16(x) @ bf16(W) via MFMA
// 16x16x32 (+ fused s1 = h@a1, s2 = h@a2); blocks [grid_gemm, +HIST_BLOCKS)
// do the coarse src-bucket histogram. Disjoint inputs -> hist traffic hides
// under gemm compute, one launch saved.
// ---------------------------------------------------------------------------
__global__ __launch_bounds__(256) void gemm_hist_kernel(
    const float* __restrict__ x, const float* __restrict__ W,
    const float* __restrict__ a, unsigned short* __restrict__ h,
    float* __restrict__ s1, float* __restrict__ s2, int N,
    const int* __restrict__ src, int* __restrict__ cbuk, int E,
    int grid_gemm) {
  __shared__ __align__(16) short Wt[64 * 136];  // W^T bf16, stride 136
  __shared__ float a_sh[2 * OUT_FEAT];
  __shared__ int lh[MAX_NBUK];

  if (blockIdx.x >= grid_gemm) {
    // ---- coarse histogram part (uniform branch per block) ----
    int t = threadIdx.x;
    for (int i = t; i < MAX_NBUK; i += 256) lh[i] = 0;
    __syncthreads();
    int hb = blockIdx.x - grid_gemm;
    for (int e = hb * 256 + t; e < E; e += HIST_BLOCKS * 256)
      atomicAdd(&lh[src[e] >> BUK_SHIFT], 1);
    __syncthreads();
    for (int i = t; i < MAX_NBUK; i += 256)
      if (lh[i] > 0) atomicAdd(&cbuk[i], lh[i]);
    return;
  }

  // ---- gemm part ----
  if (threadIdx.x < 2 * OUT_FEAT) a_sh[threadIdx.x] = a[threadIdx.x];
  for (int i = threadIdx.x; i < IN_FEAT * OUT_FEAT; i += 256) {
    int k = i >> 6, n = i & 63;
    Wt[n * 136 + k] = f2bf(W[i]);
  }
  __syncthreads();

  int wave = threadIdx.x >> 6;
  int lane = threadIdx.x & 63;
  int l = lane & 15;
  int quad = lane >> 4;

  int row_base = blockIdx.x * 64 + wave * 16;
  int m = row_base + l;
  int m_c = m < N ? m : N - 1;

  bf16x8 bfrag[4][4];
#pragma unroll
  for (int kt = 0; kt < 4; ++kt)
#pragma unroll
    for (int nt = 0; nt < 4; ++nt)
      bfrag[kt][nt] = *(const bf16x8*)&Wt[(nt * 16 + l) * 136 + kt * 32 + quad * 8];

  floatx4 acc[4] = {floatx4{0,0,0,0}, floatx4{0,0,0,0}, floatx4{0,0,0,0}, floatx4{0,0,0,0}};
  const float* xrow = x + (size_t)m_c * IN_FEAT;
#pragma unroll
  for (int kt = 0; kt < 4; ++kt) {
    float4 xa = *(const float4*)(xrow + kt * 32 + quad * 8);
    float4 xb = *(const float4*)(xrow + kt * 32 + quad * 8 + 4);
    bf16x8 af;
    af[0] = f2bf(xa.x); af[1] = f2bf(xa.y); af[2] = f2bf(xa.z); af[3] = f2bf(xa.w);
    af[4] = f2bf(xb.x); af[5] = f2bf(xb.y); af[6] = f2bf(xb.z); af[7] = f2bf(xb.w);
#pragma unroll
    for (int nt = 0; nt < 4; ++nt)
      acc[nt] = __builtin_amdgcn_mfma_f32_16x16x32_bf16(af, bfrag[kt][nt], acc[nt], 0, 0, 0);
  }

  int out_row = row_base + quad * 4;
#pragma unroll
  for (int reg = 0; reg < 4; ++reg) {
    int r = out_row + reg;
    if (r < N) {
#pragma unroll
      for (int nt = 0; nt < 4; ++nt)
        h[(size_t)r * OUT_FEAT + nt * 16 + l] = (unsigned short)f2bf(acc[nt][reg]);
    }
  }

  float p1[4] = {0, 0, 0, 0}, p2[4] = {0, 0, 0, 0};
#pragma unroll
  for (int nt = 0; nt < 4; ++nt) {
    float a1v = a_sh[nt * 16 + l];
    float a2v = a_sh[OUT_FEAT + nt * 16 + l];
#pragma unroll
    for (int reg = 0; reg < 4; ++reg) {
      p1[reg] += acc[nt][reg] * a1v;
      p2[reg] += acc[nt][reg] * a2v;
    }
  }
#pragma unroll
  for (int off = 1; off < 16; off <<= 1) {
#pragma unroll
    for (int reg = 0; reg < 4; ++reg) {
      p1[reg] += __shfl_xor(p1[reg], off);
      p2[reg] += __shfl_xor(p2[reg], off);
    }
  }
  if (l < 4) {
    int r = out_row + l;
    if (r < N) {
      float v1 = l == 0 ? p1[0] : (l == 1 ? p1[1] : (l == 2 ? p1[2] : p1[3]));
      float v2 = l == 0 ? p2[0] : (l == 1 ? p2[1] : (l == 2 ? p2[2] : p2[3]));
      s1[r] = v1;
      s2[r] = v2;
    }
  }
}

// ---------------------------------------------------------------------------
// Parallel exclusive scan of bucket counts -> buk_off (NB+1) + bin cursors.
// Two-level __shfl_up scan (16 waves of 64, then 16-element wave-sum scan).
// ---------------------------------------------------------------------------
__global__ __launch_bounds__(1024) void scan_buckets_kernel(
    const int* __restrict__ cbuk, int* __restrict__ buk_off,
    int* __restrict__ buk_cursor, int NB) {
  __shared__ int wsum[16];
  __shared__ int wexcl[16];
  int t = threadIdx.x;
  int lane = t & 63;
  int w = t >> 6;

  int v = (t < NB) ? cbuk[t] : 0;
  int x = v;
#pragma unroll
  for (int off = 1; off < 64; off <<= 1) {
    int y = __shfl_up(x, off);
    if (lane >= off) x += y;
  }
  if (lane == 63) wsum[w] = x;
  __syncthreads();
  if (t < 64) {
    int s = (t < 16) ? wsum[t] : 0;
    int xs = s;
#pragma unroll
    for (int off = 1; off < 16; off <<= 1) {
      int y = __shfl_up(xs, off);
      if (lane >= off) xs += y;
    }
    if (t < 16) wexcl[t] = xs - s;
  }
  __syncthreads();
  int excl = wexcl[w] + x - v;   // exclusive prefix over cbuk[0..t)
  if (t < NB) {
    buk_off[t] = excl;
    buk_cursor[t] = excl;
  }
  if (t == NB) buk_off[NB] = excl;                        // NB < 1024
  if (NB == 1024 && t == 1023) buk_off[NB] = excl + v;    // safety for max N
}

// ---------------------------------------------------------------------------
// Bin by src>>7. Pure routing: bukdata[pos] = (sl<<17)|dst, 4B/edge (6.4MB).
// 196 blocks (proven best count: 782 blocks cost +18us in per-block cursor
// atomics); 512 threads x 16 edges = same 8192 edges/block but 2x the waves
// to hide scattered-write + LDS-atomic latency.
// ---------------------------------------------------------------------------
__global__ __launch_bounds__(BIN_THREADS) void bin_kernel(
    const int* __restrict__ src, const int* __restrict__ dst,
    int* __restrict__ buk_cursor, int* __restrict__ bukdata, int E) {
  __shared__ int lhist[MAX_NBUK];
  __shared__ int lbase[MAX_NBUK];
  int t = threadIdx.x;
  for (int i = t; i < MAX_NBUK; i += BIN_THREADS) lhist[i] = 0;
  __syncthreads();

  int base_e = blockIdx.x * (BIN_THREADS * BIN_PER_THREAD);
  int s[BIN_PER_THREAD], d[BIN_PER_THREAD];
#pragma unroll
  for (int j = 0; j < BIN_PER_THREAD; ++j) {
    int e = base_e + j * BIN_THREADS + t;
    bool valid = e < E;
    s[j] = valid ? src[e] : 0;
    d[j] = valid ? dst[e] : 0;
    if (valid) atomicAdd(&lhist[s[j] >> BUK_SHIFT], 1);
  }
  __syncthreads();
  for (int i = t; i < MAX_NBUK; i += BIN_THREADS) {
    int c = lhist[i];
    lbase[i] = c > 0 ? atomicAdd(&buk_cursor[i], c) : 0;
    lhist[i] = 0;  // reuse as in-block cursor
  }
  __syncthreads();
#pragma unroll
  for (int j = 0; j < BIN_PER_THREAD; ++j) {
    int e = base_e + j * BIN_THREADS + t;
    if (e < E) {
      int b = s[j] >> BUK_SHIFT;
      int pos = lbase[b] + atomicAdd(&lhist[b], 1);
      bukdata[pos] = ((s[j] & (BUK_SIZE - 1)) << D_BITS) | d[j];
    }
  }
}

// ---------------------------------------------------------------------------
// Fused sort+aggregate: one 512-thread block (8 waves) per 128-node bucket
// (~2048 edges). Per chunk: stage packed edges in regs, LDS histogram, block
// scan, scatter {dst,ee} into LDS sorted by node. Aggregation walks TWO
// nodes per wave concurrently -- 2-node is the VGPR sweet spot: 52 VGPR
// (<= 64-VGPR occupancy step). 4-node measured 68 VGPR -> occupancy halved
// -> net +27% slower (round 3). Request-concurrency-bound phase: per-CU
// in-flight = per-wave x waves; don't trade waves for per-wave concurrency
// past the 64-VGPR cliff.
// ---------------------------------------------------------------------------
__global__ __launch_bounds__(512) void bucket_sort_aggregate_kernel(
    const int* __restrict__ bukdata, const int* __restrict__ buk_off,
    const float* __restrict__ s1, const float* __restrict__ s2,
    const unsigned short* __restrict__ h, float* __restrict__ out, int N) {
  __shared__ float s1sh[BUK_SIZE];
  __shared__ int lhist[BUK_SIZE];
  __shared__ int loffs[BUK_SIZE];
  __shared__ int lcur[BUK_SIZE];
  __shared__ int wtot[2];
  __shared__ int2 lrec[CAP];  // 20KB

  int t = threadIdx.x;
  int buk = blockIdx.x;
  int beg = buk_off[buk];
  int end = buk_off[buk + 1];
  int node_base = buk << BUK_SHIFT;

  if (t < BUK_SIZE) {
    int ng = node_base + t;
    s1sh[t] = ng < N ? s1[ng] : 0.f;
  }

  int wid = t >> 6;      // wave 0..7; owns nodes wid, wid+8, ..., wid+120
  int lane = t & 63;
  int half = lane >> 5;
  int c2 = lane & 31;

  float ax[16], ay[16], rs[16];
#pragma unroll
  for (int j = 0; j < 16; ++j) { ax[j] = 0.f; ay[j] = 0.f; rs[j] = 0.f; }

  for (int cbeg = beg; cbeg < end; cbeg += CAP) {
    int cnt = min(end - cbeg, CAP);

    if (t < BUK_SIZE) lhist[t] = 0;
    __syncthreads();  // also covers s1sh on first chunk

    // ---- Stage: load packed edges, compute ee once/edge, LDS histogram ----
    int dreg[STAGE_MAX];
    int slreg[STAGE_MAX];
    float ereg[STAGE_MAX];
#pragma unroll
    for (int j = 0; j < STAGE_MAX; ++j) {
      int i = t + j * 512;
      bool v = i < cnt;
      int pk = v ? bukdata[cbeg + i] : 0;
      slreg[j] = pk >> D_BITS;
      dreg[j] = pk & D_MASK;
      float sc = s1sh[slreg[j]] + (v ? s2[dreg[j]] : 0.f);
      ereg[j] = __expf(-(sc > 0.f ? sc : LRELU_ALPHA * sc));
      if (v) atomicAdd(&lhist[slreg[j]], 1);
    }
    __syncthreads();

    // ---- Block scan over 128 counters (threads 0..127, 2 waves) ----
    int hv = (t < BUK_SIZE) ? lhist[t] : 0;
    int xs = hv;
#pragma unroll
    for (int off = 1; off < 64; off <<= 1) {
      int y = __shfl_up(xs, off);
      if (lane >= off) xs += y;
    }
    if (t < BUK_SIZE && lane == 63) wtot[t >> 6] = xs;
    __syncthreads();
    if (t < BUK_SIZE) {
      int base = (t >> 6) ? wtot[0] : 0;
      int excl = base + xs - hv;
      loffs[t] = excl;
      lcur[t] = excl;
    }
    __syncthreads();

    // ---- Scatter into LDS, sorted by node ----
#pragma unroll
    for (int j = 0; j < STAGE_MAX; ++j) {
      int i = t + j * 512;
      if (i < cnt) {
        int pos = atomicAdd(&lcur[slreg[j]], 1);
        lrec[pos] = make_int2(dreg[j], __float_as_int(ereg[j]));
      }
    }
    __syncthreads();

    // ---- Aggregate: 2 nodes per wave in flight (independent chains) ----
#pragma unroll
    for (int p = 0; p < 8; ++p) {
      int nlA = wid + (2 * p) * 8;
      int nlB = wid + (2 * p + 1) * 8;
      int cA = lhist[nlA];
      int cB = lhist[nlB];
      int oA = cA > 0 ? loffs[nlA] : 0;  // clamp: lrec[0] valid (cnt>=1)
      int oB = cB > 0 ? loffs[nlB] : 0;
      int kmax = cA > cB ? cA : cB;
      for (int k = 0; k < kmax; k += 8) {   // trip count wave-uniform
#pragma unroll
        for (int j = 0; j < 4; ++j) {
          int idx = k + 2 * j + half;
          bool vA = idx < cA;
          bool vB = idx < cB;
          int2 rA = lrec[oA + (vA ? idx : 0)];   // in-bounds: <= oA+cA-1 < cnt
          int2 rB = lrec[oB + (vB ? idx : 0)];
          float eA = vA ? __int_as_float(rA.y) : 0.f;
          float eB = vB ? __int_as_float(rB.y) : 0.f;
          unsigned hA = *(const unsigned*)&h[rA.x * OUT_FEAT + 2 * c2];
          unsigned hB = *(const unsigned*)&h[rB.x * OUT_FEAT + 2 * c2];
          rs[2 * p]     += eA;
          ax[2 * p]     += eA * bf2f(hA & 0xffff);
          ay[2 * p]     += eA * bf2f(hA >> 16);
          rs[2 * p + 1] += eB;
          ax[2 * p + 1] += eB * bf2f(hB & 0xffff);
          ay[2 * p + 1] += eB * bf2f(hB >> 16);
        }
      }
    }
    __syncthreads();  // protect lhist/loffs/lrec before next chunk
  }

  // ---- Finalize: cross-half reduce, out = elu(acc / rowsum) ----
#pragma unroll
  for (int nn = 0; nn < 16; ++nn) {
    float r = rs[nn] + __shfl_xor(rs[nn], 32);
    float xv = ax[nn] + __shfl_xor(ax[nn], 32);
    float yv = ay[nn] + __shfl_xor(ay[nn], 32);
    int ng = node_base + wid + nn * 8;
    if (ng < N && half == 0) {
      float vx = xv / r, vy = yv / r;
      vx = vx > 0.f ? vx : __expf(vx) - 1.f;
      vy = vy > 0.f ? vy : __expf(vy) - 1.f;
      *(float2*)&out[(size_t)ng * OUT_FEAT + 2 * c2] = make_float2(vx, vy);
    }
  }
}

extern "C" void kernel_launch(void* const* d_in, const int* in_sizes, int n_in,
                              void* d_out, int out_size, void* d_ws, size_t ws_size,
                              hipStream_t stream) {
  const float* x = (const float*)d_in[0];  // (N, 128) fp32
  const float* W = (const float*)d_in[1];  // (128, 64) fp32
  const float* a = (const float*)d_in[2];  // (1, 128) fp32
  const int* edge = (const int*)d_in[3];   // (2, E) int32

  const int N = in_sizes[0] / IN_FEAT;
  const int E = in_sizes[3] / 2;
  const int* src = edge;
  const int* dst = edge + E;

  float* out = (float*)d_out;  // (N, 64) fp32

  // Workspace layout (~21 MB)
  char* p = (char*)d_ws;
  unsigned short* h = (unsigned short*)p; p += (size_t)N * OUT_FEAT * sizeof(unsigned short);
  float* s1 = (float*)p;      p += (size_t)N * sizeof(float);
  float* s2 = (float*)p;      p += (size_t)N * sizeof(float);
  int* cbuk = (int*)p;        p += MAX_NBUK * sizeof(int);
  int* buk_off = (int*)p;     p += (MAX_NBUK + 1) * sizeof(int);
  int* buk_cursor = (int*)p;  p += MAX_NBUK * sizeof(int);
  int* bukdata = (int*)p;     p += (size_t)E * sizeof(int);

  const int NB = (N + BUK_SIZE - 1) / BUK_SIZE;  // 782 buckets

  hipMemsetAsync(cbuk, 0, MAX_NBUK * sizeof(int), stream);

  int grid_gemm = (N + 63) / 64;
  gemm_hist_kernel<<<grid_gemm + HIST_BLOCKS, 256, 0, stream>>>(
      x, W, a, h, s1, s2, N, src, cbuk, E, grid_gemm);

  scan_buckets_kernel<<<1, 1024, 0, stream>>>(cbuk, buk_off, buk_cursor, NB);

  int grid_bin = (E + BIN_THREADS * BIN_PER_THREAD - 1) / (BIN_THREADS * BIN_PER_THREAD);
  bin_kernel<<<grid_bin, BIN_THREADS, 0, stream>>>(src, dst, buk_cursor, bukdata, E);

  bucket_sort_aggregate_kernel<<<NB, 512, 0, stream>>>(bukdata, buk_off, s1, s2, h, out, N);
}